// Round 7
// baseline (680.467 us; speedup 1.0000x reference)
//
#include <hip/hip_runtime.h>
#include <math.h>

#define BB      2
#define CC      512
#define NN_TOK  4096
#define HEADS   8
#define DHEAD   64
#define HID     512
#define GROUPS  32
#define CPG     (CC / GROUPS)
#define EPS     1e-5f

typedef __bf16 bf16x8 __attribute__((ext_vector_type(8)));
typedef float  f32x4  __attribute__((ext_vector_type(4)));
typedef float  f32x16 __attribute__((ext_vector_type(16)));

static __device__ __forceinline__ unsigned short f2bf(float f) {
  __bf16 h = (__bf16)f;
  return __builtin_bit_cast(unsigned short, h);
}
static __device__ __forceinline__ unsigned packbf(float a, float b) {
  return (unsigned)f2bf(a) | ((unsigned)f2bf(b) << 16);
}

// ---------------------------------------------------------------------------
// Convert 4 fp32 512x512 weights to bf16.
// ---------------------------------------------------------------------------
__global__ __launch_bounds__(256) void wconv_kernel(
    const float* __restrict__ w0, const float* __restrict__ w1,
    const float* __restrict__ w2, const float* __restrict__ w3,
    unsigned short* __restrict__ o0, unsigned short* __restrict__ o1,
    unsigned short* __restrict__ o2, unsigned short* __restrict__ o3) {
  int y = blockIdx.y;
  const float* src = (y == 0) ? w0 : (y == 1) ? w1 : (y == 2) ? w2 : w3;
  unsigned short* dst = (y == 0) ? o0 : (y == 1) ? o1 : (y == 2) ? o2 : o3;
  int idx = (blockIdx.x * 256 + threadIdx.x) * 8;
  float4 a = *(const float4*)&src[idx];
  float4 b = *(const float4*)&src[idx + 4];
  ushort4 p0, p1;
  p0.x = f2bf(a.x); p0.y = f2bf(a.y); p0.z = f2bf(a.z); p0.w = f2bf(a.w);
  p1.x = f2bf(b.x); p1.y = f2bf(b.y); p1.z = f2bf(b.z); p1.w = f2bf(b.w);
  *(ushort4*)&dst[idx] = p0;
  *(ushort4*)&dst[idx + 4] = p1;
}

// ---------------------------------------------------------------------------
// GroupNorm stats: one block per quarter-group. grid 256.
// ---------------------------------------------------------------------------
__global__ __launch_bounds__(256) void gn_stats_kernel(
    const float* __restrict__ x, float2* __restrict__ part) {
  int blk = blockIdx.x;
  const float4* __restrict__ x4 = (const float4*)(x + (size_t)blk * 16384);
  int t = threadIdx.x;
  float s = 0.f, ss = 0.f;
  #pragma unroll
  for (int i = 0; i < 16; ++i) {
    float4 v = x4[t + i * 256];
    s  += v.x + v.y + v.z + v.w;
    ss += v.x * v.x + v.y * v.y + v.z * v.z + v.w * v.w;
  }
  #pragma unroll
  for (int off = 32; off >= 1; off >>= 1) {
    s  += __shfl_down(s, off, 64);
    ss += __shfl_down(ss, off, 64);
  }
  __shared__ float rs[4], rss[4];
  int wid = t >> 6, lane = t & 63;
  if (lane == 0) { rs[wid] = s; rss[wid] = ss; }
  __syncthreads();
  if (t == 0) {
    float2 o;
    o.x = rs[0] + rs[1] + rs[2] + rs[3];
    o.y = rss[0] + rss[1] + rss[2] + rss[3];
    part[blk] = o;
  }
}

// ---------------------------------------------------------------------------
// GroupNorm apply -> bf16 [b][c][tok]. grid 256.
// ---------------------------------------------------------------------------
__global__ __launch_bounds__(256) void gn_apply_kernel(
    const float* __restrict__ x, const float* __restrict__ gamma,
    const float* __restrict__ beta, const float2* __restrict__ part,
    unsigned short* __restrict__ xnb) {
  int blk = blockIdx.x;
  int gi = blk >> 2, qtr = blk & 3;
  int g = gi & 31;
  float2 p0 = part[gi * 4 + 0], p1 = part[gi * 4 + 1];
  float2 p2 = part[gi * 4 + 2], p3 = part[gi * 4 + 3];
  float S = p0.x + p1.x + p2.x + p3.x;
  float SS = p0.y + p1.y + p2.y + p3.y;
  const float inv_n = 1.0f / (float)(CPG * NN_TOK);
  float mu = S * inv_n;
  float var = SS * inv_n - mu * mu;
  float rstd = rsqrtf(var + EPS);

  const size_t base = (size_t)blk * 16384;
  const float4* __restrict__ xin4 = (const float4*)(x + base);
  unsigned short* __restrict__ xo = xnb + base;
  int t = threadIdx.x;
  #pragma unroll
  for (int i = 0; i < 8; ++i) {
    int f = t + i * 256;
    int c_local = f >> 9;
    int c = g * CPG + qtr * 4 + c_local;
    float ga = gamma[c] * rstd;
    float be = beta[c] - mu * ga;
    float4 a = xin4[2 * f];
    float4 d = xin4[2 * f + 1];
    ushort4 q0, q1;
    q0.x = f2bf(a.x * ga + be); q0.y = f2bf(a.y * ga + be);
    q0.z = f2bf(a.z * ga + be); q0.w = f2bf(a.w * ga + be);
    q1.x = f2bf(d.x * ga + be); q1.y = f2bf(d.y * ga + be);
    q1.z = f2bf(d.z * ga + be); q1.w = f2bf(d.w * ga + be);
    *(ushort4*)&xo[f * 8] = q0;
    *(ushort4*)&xo[f * 8 + 4] = q1;
  }
}

// ---------------------------------------------------------------------------
// Transpose bf16 [b][c][tok] -> [b][tok][c]. 64x64 tiles.
// ---------------------------------------------------------------------------
__global__ __launch_bounds__(256) void transpose_kernel(
    const unsigned short* __restrict__ in, unsigned short* __restrict__ outT) {
  __shared__ __align__(16) unsigned short lds[64 * 72];
  int b = blockIdx.z;
  int t0 = blockIdx.x * 64, c0 = blockIdx.y * 64;
  const unsigned short* __restrict__ inb = in + (size_t)b * CC * NN_TOK;
  unsigned short* __restrict__ ob = outT + (size_t)b * NN_TOK * CC;
  int t = threadIdx.x;
  #pragma unroll
  for (int i = 0; i < 2; ++i) {
    int f = t + i * 256;
    int row = f >> 3, ch = f & 7;
    *(uint4*)&lds[row * 72 + ch * 8] =
        *(const uint4*)&inb[(size_t)(c0 + row) * NN_TOK + t0 + ch * 8];
  }
  __syncthreads();
  #pragma unroll
  for (int i = 0; i < 2; ++i) {
    int f = t + i * 256;
    int row = f >> 3, ch = f & 7;
    ushort4 a, b4;
    a.x  = lds[(ch * 8 + 0) * 72 + row];
    a.y  = lds[(ch * 8 + 1) * 72 + row];
    a.z  = lds[(ch * 8 + 2) * 72 + row];
    a.w  = lds[(ch * 8 + 3) * 72 + row];
    b4.x = lds[(ch * 8 + 4) * 72 + row];
    b4.y = lds[(ch * 8 + 5) * 72 + row];
    b4.z = lds[(ch * 8 + 6) * 72 + row];
    b4.w = lds[(ch * 8 + 7) * 72 + row];
    *(ushort4*)&ob[(size_t)(t0 + row) * CC + c0 + ch * 8] = a;
    *(ushort4*)&ob[(size_t)(t0 + row) * CC + c0 + ch * 8 + 4] = b4;
  }
}

// ---------------------------------------------------------------------------
// Fused Q/K/V MFMA GEMM (round-3 structure).
// ---------------------------------------------------------------------------
__global__ __launch_bounds__(256) void qkv_gemm_kernel(
    const unsigned short* __restrict__ xnT,
    const unsigned short* __restrict__ wqb, const unsigned short* __restrict__ wkb,
    const unsigned short* __restrict__ wvb,
    const float* __restrict__ bq, const float* __restrict__ bk,
    const float* __restrict__ bv,
    unsigned short* __restrict__ qT, unsigned short* __restrict__ kT,
    unsigned short* __restrict__ vB) {
  __shared__ __align__(16) unsigned short AsBs[2 * 128 * 72];
  unsigned short* As = AsBs;
  unsigned short* Bs = AsBs + 128 * 72;
  int b = blockIdx.z;
  int y = blockIdx.y;
  int which = y >> 2, yl = y & 3;
  const unsigned short* __restrict__ W =
      (which == 0) ? wqb : (which == 1) ? wkb : wvb;
  const float* __restrict__ bias = (which == 0) ? bq : (which == 1) ? bk : bv;
  int m0 = yl * 128;
  int n0 = blockIdx.x * 128;
  const unsigned short* __restrict__ Bsrc = xnT + (size_t)b * NN_TOK * CC;
  int t = threadIdx.x, w = t >> 6, lane = t & 63;
  int wm = (w >> 1) * 64, wn = (w & 1) * 64;
  int l15 = lane & 15, lq = lane >> 4;

  f32x4 acc[4][4];
  #pragma unroll
  for (int mt = 0; mt < 4; ++mt)
    #pragma unroll
    for (int nt = 0; nt < 4; ++nt) acc[mt][nt] = (f32x4){0.f, 0.f, 0.f, 0.f};

  for (int kc = 0; kc < CC; kc += 64) {
    __syncthreads();
    #pragma unroll
    for (int i = 0; i < 4; ++i) {
      int f = t + i * 256;
      int row = f >> 3, ch = f & 7;
      *(uint4*)&As[row * 72 + ch * 8] =
          *(const uint4*)&W[(size_t)(m0 + row) * CC + kc + ch * 8];
      *(uint4*)&Bs[row * 72 + ch * 8] =
          *(const uint4*)&Bsrc[(size_t)(n0 + row) * CC + kc + ch * 8];
    }
    __syncthreads();
    #pragma unroll
    for (int ks = 0; ks < 2; ++ks) {
      bf16x8 af[4], bfr[4];
      #pragma unroll
      for (int i = 0; i < 4; ++i) {
        af[i]  = *(const bf16x8*)&As[(wm + i * 16 + l15) * 72 + ks * 32 + lq * 8];
        bfr[i] = *(const bf16x8*)&Bs[(wn + i * 16 + l15) * 72 + ks * 32 + lq * 8];
      }
      #pragma unroll
      for (int mt = 0; mt < 4; ++mt)
        #pragma unroll
        for (int nt = 0; nt < 4; ++nt)
          acc[mt][nt] = __builtin_amdgcn_mfma_f32_16x16x32_bf16(
              af[mt], bfr[nt], acc[mt][nt], 0, 0, 0);
    }
  }
  __syncthreads();

  if (which < 2) {
    const float sc = (which == 0) ? 0.18033688011112043f : 1.0f; // 0.125*log2e
    unsigned short* __restrict__ dstT = (which == 0) ? qT : kT;
    unsigned short* buf = AsBs + w * 2304;
    int h = (m0 + wm) >> 6;
    const size_t hbase = (size_t)(b * HEADS + h) * NN_TOK;
    #pragma unroll
    for (int p = 0; p < 2; ++p) {
      #pragma unroll
      for (int mt = 0; mt < 4; ++mt) {
        float4 bv4 = *(const float4*)&bias[m0 + wm + mt * 16 + lq * 4];
        #pragma unroll
        for (int ntl = 0; ntl < 2; ++ntl) {
          int nt = p * 2 + ntl;
          f32x4 a = acc[mt][nt];
          ushort4 pk;
          pk.x = f2bf((a[0] + bv4.x) * sc);
          pk.y = f2bf((a[1] + bv4.y) * sc);
          pk.z = f2bf((a[2] + bv4.z) * sc);
          pk.w = f2bf((a[3] + bv4.w) * sc);
          *(ushort4*)&buf[(ntl * 16 + l15) * 72 + mt * 16 + lq * 4] = pk;
        }
      }
      #pragma unroll
      for (int it = 0; it < 4; ++it) {
        int idx = it * 64 + lane;
        int row = idx >> 3, ch = idx & 7;
        int tok = n0 + wn + p * 32 + row;
        *(uint4*)&dstT[(hbase + tok) * DHEAD + ch * 8] =
            *(const uint4*)&buf[row * 72 + ch * 8];
      }
    }
  } else {
    unsigned short* __restrict__ dst = vB + (size_t)b * HID * NN_TOK;
    #pragma unroll
    for (int mt = 0; mt < 4; ++mt) {
      float4 bv4 = *(const float4*)&bias[m0 + wm + mt * 16 + lq * 4];
      float bvr[4] = {bv4.x, bv4.y, bv4.z, bv4.w};
      #pragma unroll
      for (int nt = 0; nt < 4; ++nt) {
        int tok = n0 + wn + nt * 16 + l15;
        #pragma unroll
        for (int r = 0; r < 4; ++r) {
          int m = m0 + wm + mt * 16 + lq * 4 + r;
          dst[(size_t)m * NN_TOK + tok] = f2bf(acc[mt][nt][r] + bvr[r]);
        }
      }
    }
  }
}

// ---------------------------------------------------------------------------
// Out-proj MFMA GEMM: out = wo*ao^T + bo + x.
// ---------------------------------------------------------------------------
__global__ __launch_bounds__(256) void outproj_kernel(
    const unsigned short* __restrict__ aoT, const unsigned short* __restrict__ wob,
    const float* __restrict__ bo, const float* __restrict__ x,
    float* __restrict__ out) {
  __shared__ __align__(16) unsigned short AsBs[2 * 128 * 72];
  unsigned short* As = AsBs;
  unsigned short* Bs = AsBs + 128 * 72;
  int b = blockIdx.z;
  int m0 = blockIdx.y * 128;
  int n0 = blockIdx.x * 128;
  const unsigned short* __restrict__ Bsrc = aoT + (size_t)b * NN_TOK * HID;
  int t = threadIdx.x, w = t >> 6, lane = t & 63;
  int wm = (w >> 1) * 64, wn = (w & 1) * 64;
  int l15 = lane & 15, lq = lane >> 4;

  f32x4 acc[4][4];
  #pragma unroll
  for (int mt = 0; mt < 4; ++mt)
    #pragma unroll
    for (int nt = 0; nt < 4; ++nt) acc[mt][nt] = (f32x4){0.f, 0.f, 0.f, 0.f};

  for (int kc = 0; kc < HID; kc += 64) {
    __syncthreads();
    #pragma unroll
    for (int i = 0; i < 4; ++i) {
      int f = t + i * 256;
      int row = f >> 3, ch = f & 7;
      *(uint4*)&As[row * 72 + ch * 8] =
          *(const uint4*)&wob[(size_t)(m0 + row) * HID + kc + ch * 8];
      *(uint4*)&Bs[row * 72 + ch * 8] =
          *(const uint4*)&Bsrc[(size_t)(n0 + row) * HID + kc + ch * 8];
    }
    __syncthreads();
    #pragma unroll
    for (int ks = 0; ks < 2; ++ks) {
      bf16x8 af[4], bfr[4];
      #pragma unroll
      for (int i = 0; i < 4; ++i) {
        af[i]  = *(const bf16x8*)&As[(wm + i * 16 + l15) * 72 + ks * 32 + lq * 8];
        bfr[i] = *(const bf16x8*)&Bs[(wn + i * 16 + l15) * 72 + ks * 32 + lq * 8];
      }
      #pragma unroll
      for (int mt = 0; mt < 4; ++mt)
        #pragma unroll
        for (int nt = 0; nt < 4; ++nt)
          acc[mt][nt] = __builtin_amdgcn_mfma_f32_16x16x32_bf16(
              af[mt], bfr[nt], acc[mt][nt], 0, 0, 0);
    }
  }

  const float* __restrict__ xb = x + (size_t)b * CC * NN_TOK;
  float* __restrict__ ob = out + (size_t)b * CC * NN_TOK;
  #pragma unroll
  for (int mt = 0; mt < 4; ++mt) {
    float4 bv4 = *(const float4*)&bo[m0 + wm + mt * 16 + lq * 4];
    float bvr[4] = {bv4.x, bv4.y, bv4.z, bv4.w};
    #pragma unroll
    for (int nt = 0; nt < 4; ++nt) {
      int tok = n0 + wn + nt * 16 + l15;
      #pragma unroll
      for (int r = 0; r < 4; ++r) {
        int m = m0 + wm + mt * 16 + lq * 4 + r;
        size_t off = (size_t)m * NN_TOK + tok;
        ob[off] = acc[mt][nt][r] + bvr[r] + xb[off];
      }
    }
  }
}

// ---------------------------------------------------------------------------
// MFMA flash attention, round 7: round-6 per-wave structure (i-width 64,
// every K/V fragment feeds 2 MFMAs; P kept in registers, repacked to PV
// B-operand with one __shfl_xor(32) pair per K-step) at round-5 occupancy:
// 512 thr = 8 waves = 2 i-strips x 4 j-quarters; 256 j staged per iter
// (16 iters). Grid (32,16) = 512 blocks -> 4096 waves = 4 waves/SIMD,
// 2 blocks/CU (74.7 KB LDS). Plain stride-72 tiles. No-shift exp2 softmax.
// Epilogue: 4 partials combined via 2-level LDS tree.
// ---------------------------------------------------------------------------
__global__ __launch_bounds__(512, 4) void attn_mfma_kernel(
    const unsigned short* __restrict__ qT, const unsigned short* __restrict__ kT,
    const unsigned short* __restrict__ vv, unsigned short* __restrict__ aoT) {
  __shared__ __align__(16) unsigned short kv[36864]; // K [j256][72] | V 4x[d64][72]
  __shared__ float lbuf[2][128];
  unsigned short* ksb = kv;
  unsigned short* vsb = kv + 18432;
  int bh = blockIdx.y;
  int b = bh >> 3, h = bh & 7;
  int i0 = blockIdx.x * 128;
  const size_t hb = (size_t)bh * NN_TOK;
  const unsigned short* __restrict__ qtg = qT + hb * DHEAD;
  const unsigned short* __restrict__ ktg = kT + hb * DHEAD;
  const unsigned short* __restrict__ vg  = vv + hb * DHEAD;
  int t = threadIdx.x;
  int w = t >> 6, lane = t & 63, l31 = lane & 31, q1 = lane >> 5;
  int strip = w & 1, quarter = w >> 1;
  int iw = i0 + strip * 64;

  // Q fragments for the wave's 2 sub-strips (resident whole kernel)
  bf16x8 qf[2][4];
  #pragma unroll
  for (int su = 0; su < 2; ++su)
    #pragma unroll
    for (int s = 0; s < 4; ++s)
      qf[su][s] = *(const bf16x8*)&qtg[(size_t)(iw + su * 32 + l31) * DHEAD +
                                       s * 16 + q1 * 8];

  f32x16 oacc[2][2];                 // [sub-strip][d-half]
  #pragma unroll
  for (int su = 0; su < 2; ++su)
    #pragma unroll
    for (int dm = 0; dm < 2; ++dm)
      #pragma unroll
      for (int r = 0; r < 16; ++r) oacc[su][dm][r] = 0.f;
  float lrun[2] = {0.f, 0.f};

  const unsigned short* __restrict__ ksq = ksb + quarter * 4608;
  const unsigned short* __restrict__ vsq = vsb + quarter * 4608;

  for (int rt = 0; rt < NN_TOK / 256; ++rt) {
    int j0 = rt * 256;
    __syncthreads();
    // stage K [j 256][d 64] and V 4 tiles [d 64][j 64], 512 thr x 4 uint4 each
    #pragma unroll
    for (int i = 0; i < 4; ++i) {
      int f = t + i * 512;                 // 0..2047
      int jr = f >> 3, ch = f & 7;
      *(uint4*)&ksb[jr * 72 + ch * 8] =
          *(const uint4*)&ktg[(size_t)(j0 + jr) * DHEAD + ch * 8];
      int tile = f >> 9, rr = (f >> 3) & 63;
      *(uint4*)&vsb[tile * 4608 + rr * 72 + ch * 8] =
          *(const uint4*)&vg[(size_t)rr * NN_TOK + j0 + tile * 64 + ch * 8];
    }
    __syncthreads();

    // S^T = K (A) x Q (B) on this wave's j-quarter
    f32x16 sacc[2][2];                 // [su][j-half]
    #pragma unroll
    for (int su = 0; su < 2; ++su)
      #pragma unroll
      for (int jm = 0; jm < 2; ++jm)
        #pragma unroll
        for (int r = 0; r < 16; ++r) sacc[su][jm][r] = 0.f;
    #pragma unroll
    for (int s = 0; s < 4; ++s) {
      int slot = s * 16 + q1 * 8;
      bf16x8 a0 = *(const bf16x8*)&ksq[l31 * 72 + slot];
      bf16x8 a1 = *(const bf16x8*)&ksq[(32 + l31) * 72 + slot];
      #pragma unroll
      for (int su = 0; su < 2; ++su) {
        sacc[su][0] = __builtin_amdgcn_mfma_f32_32x32x16_bf16(a0, qf[su][s], sacc[su][0], 0, 0, 0);
        sacc[su][1] = __builtin_amdgcn_mfma_f32_32x32x16_bf16(a1, qf[su][s], sacc[su][1], 0, 0, 0);
      }
    }

    // exp2 (no shift) + pack to dwords in j-order
    unsigned dw[2][16];
    #pragma unroll
    for (int su = 0; su < 2; ++su) {
      float psum = 0.f;
      #pragma unroll
      for (int jm = 0; jm < 2; ++jm) {
        #pragma unroll
        for (int m = 0; m < 8; ++m) {
          float pa = __builtin_amdgcn_exp2f(sacc[su][jm][2 * m]);
          float pb = __builtin_amdgcn_exp2f(sacc[su][jm][2 * m + 1]);
          psum += pa + pb;
          dw[su][jm * 8 + m] = packbf(pa, pb);
        }
      }
      psum += __shfl_xor(psum, 32);
      lrun[su] += psum;
    }

    // PV: O^T = V^T (A) x P^T (B); P B-frags built in-register via shfl
    #pragma unroll
    for (int s = 0; s < 4; ++s) {
      int slot = s * 16 + q1 * 8;
      bf16x8 va0 = *(const bf16x8*)&vsq[l31 * 72 + slot];
      bf16x8 va1 = *(const bf16x8*)&vsq[(32 + l31) * 72 + slot];
      #pragma unroll
      for (int su = 0; su < 2; ++su) {
        int base = (s >> 1) * 8 + (s & 1) * 4;
        unsigned m0 = dw[su][base], m1 = dw[su][base + 1];
        unsigned m2 = dw[su][base + 2], m3 = dw[su][base + 3];
        unsigned y0 = q1 ? m0 : m2;
        unsigned y1 = q1 ? m1 : m3;
        unsigned z0 = (unsigned)__shfl_xor((int)y0, 32);
        unsigned z1 = (unsigned)__shfl_xor((int)y1, 32);
        uint4 fr;
        fr.x = q1 ? z0 : m0;
        fr.y = q1 ? z1 : m1;
        fr.z = q1 ? m2 : z0;
        fr.w = q1 ? m3 : z1;
        bf16x8 pb = __builtin_bit_cast(bf16x8, fr);
        oacc[su][0] = __builtin_amdgcn_mfma_f32_32x32x16_bf16(va0, pb, oacc[su][0], 0, 0, 0);
        oacc[su][1] = __builtin_amdgcn_mfma_f32_32x32x16_bf16(va1, pb, oacc[su][1], 0, 0, 0);
      }
    }
  }

  // ---- 4-way partial combine: 2-level LDS tree ----
  __syncthreads();
  float* obufA = (float*)kv;           // [d 64][i 128] 32 KB
  float* obufB = obufA + 8192;         // [d 64][i 128] 32 KB
  if (quarter >= 2) {
    float* ob = (quarter == 2) ? obufA : obufB;
    float* lb = (quarter == 2) ? lbuf[0] : lbuf[1];
    #pragma unroll
    for (int su = 0; su < 2; ++su) {
      int iloc = strip * 64 + su * 32 + l31;
      #pragma unroll
      for (int dm = 0; dm < 2; ++dm)
        #pragma unroll
        for (int r = 0; r < 16; ++r) {
          int d = dm * 32 + (r & 3) + 8 * (r >> 2) + 4 * q1;
          ob[d * 128 + iloc] = oacc[su][dm][r];
        }
      if (q1 == 0) lb[iloc] = lrun[su];
    }
  }
  __syncthreads();
  if (quarter < 2) {
    float* ob = (quarter == 0) ? obufA : obufB;
    float* lb = (quarter == 0) ? lbuf[0] : lbuf[1];
    #pragma unroll
    for (int su = 0; su < 2; ++su) {
      int iloc = strip * 64 + su * 32 + l31;
      #pragma unroll
      for (int dm = 0; dm < 2; ++dm)
        #pragma unroll
        for (int r = 0; r < 16; ++r) {
          int d = dm * 32 + (r & 3) + 8 * (r >> 2) + 4 * q1;
          oacc[su][dm][r] += ob[d * 128 + iloc];
        }
      lrun[su] += lb[iloc];
    }
  }
  __syncthreads();
  if (quarter == 1) {
    #pragma unroll
    for (int su = 0; su < 2; ++su) {
      int iloc = strip * 64 + su * 32 + l31;
      #pragma unroll
      for (int dm = 0; dm < 2; ++dm)
        #pragma unroll
        for (int r = 0; r < 16; ++r) {
          int d = dm * 32 + (r & 3) + 8 * (r >> 2) + 4 * q1;
          obufA[d * 128 + iloc] = oacc[su][dm][r];
        }
      if (q1 == 0) lbuf[0][iloc] = lrun[su];
    }
  }
  __syncthreads();
  if (quarter == 0) {
    unsigned short* st = (unsigned short*)(obufA + 8192); // 2 x [64][72]
    unsigned short* stw = st + strip * 4608;
    #pragma unroll
    for (int su = 0; su < 2; ++su) {
      int iloc = strip * 64 + su * 32 + l31;
      float ltot = lrun[su] + lbuf[0][iloc];
      float inv = 1.0f / ltot;
      #pragma unroll
      for (int dm = 0; dm < 2; ++dm) {
        #pragma unroll
        for (int g = 0; g < 4; ++g) {
          float v[4];
          #pragma unroll
          for (int i = 0; i < 4; ++i) {
            int r = 4 * g + i;
            int d = dm * 32 + i + 8 * g + 4 * q1;
            v[i] = (oacc[su][dm][r] + obufA[d * 128 + iloc]) * inv;
          }
          ushort4 pk;
          pk.x = f2bf(v[0]); pk.y = f2bf(v[1]); pk.z = f2bf(v[2]); pk.w = f2bf(v[3]);
          *(ushort4*)&stw[(su * 32 + l31) * 72 + dm * 32 + g * 8 + q1 * 4] = pk;
        }
      }
    }
    const size_t obase = (size_t)b * NN_TOK;
    #pragma unroll
    for (int it = 0; it < 8; ++it) {
      int idx = it * 64 + lane;
      int row = idx >> 3, ch = idx & 7;
      int tok = iw + row;
      *(uint4*)&aoT[(obase + tok) * HID + h * DHEAD + ch * 8] =
          *(const uint4*)&stw[row * 72 + ch * 8];
    }
  }
}

// ---------------------------------------------------------------------------
extern "C" void kernel_launch(void* const* d_in, const int* in_sizes, int n_in,
                              void* d_out, int out_size, void* d_ws, size_t ws_size,
                              hipStream_t stream) {
  const float* x     = (const float*)d_in[0];
  const float* gamma = (const float*)d_in[1];
  const float* beta  = (const float*)d_in[2];
  const float* wq    = (const float*)d_in[3];
  const float* bq    = (const float*)d_in[4];
  const float* wk    = (const float*)d_in[5];
  const float* bk    = (const float*)d_in[6];
  const float* wv    = (const float*)d_in[7];
  const float* bv    = (const float*)d_in[8];
  const float* wo    = (const float*)d_in[9];
  const float* bo    = (const float*)d_in[10];
  float* out = (float*)d_out;

  const size_t SZ = (size_t)BB * CC * NN_TOK;
  const size_t WZ = (size_t)CC * HID;
  unsigned short* xnb = (unsigned short*)d_ws;
  unsigned short* xnT = xnb + SZ;
  unsigned short* qT  = xnT + SZ;
  unsigned short* kT  = qT + SZ;
  unsigned short* vB  = kT + SZ;
  unsigned short* aoT = vB + SZ;
  unsigned short* wqb = aoT + SZ;
  unsigned short* wkb = wqb + WZ;
  unsigned short* wvb = wkb + WZ;
  unsigned short* wob = wvb + WZ;
  float2* gnpart = (float2*)(wob + WZ);

  wconv_kernel<<<dim3(128, 4), dim3(256), 0, stream>>>(
      wq, wk, wv, wo, wqb, wkb, wvb, wob);

  gn_stats_kernel<<<dim3(256), dim3(256), 0, stream>>>(x, gnpart);
  gn_apply_kernel<<<dim3(256), dim3(256), 0, stream>>>(
      x, gamma, beta, gnpart, xnb);

  transpose_kernel<<<dim3(NN_TOK / 64, CC / 64, BB), dim3(256), 0, stream>>>(
      xnb, xnT);

  qkv_gemm_kernel<<<dim3(NN_TOK / 128, 12, BB), dim3(256), 0, stream>>>(
      xnT, wqb, wkb, wvb, bq, bk, bv, qT, kT, vB);

  attn_mfma_kernel<<<dim3(NN_TOK / 128, BB * HEADS), dim3(512), 0, stream>>>(
      qT, kT, vB, aoT);

  outproj_kernel<<<dim3(NN_TOK / 128, CC / 128, BB), dim3(256), 0, stream>>>(
      aoT, wob, bo, x, out);
}

// Round 8
// 225.195 us; speedup vs baseline: 3.0217x; 3.0217x over previous
//
#include <hip/hip_runtime.h>
#include <math.h>

#define BB      2
#define CC      512
#define NN_TOK  4096
#define HEADS   8
#define DHEAD   64
#define HID     512
#define GROUPS  32
#define CPG     (CC / GROUPS)
#define EPS     1e-5f

typedef __bf16 bf16x8 __attribute__((ext_vector_type(8)));
typedef float  f32x4  __attribute__((ext_vector_type(4)));
typedef float  f32x16 __attribute__((ext_vector_type(16)));

static __device__ __forceinline__ unsigned short f2bf(float f) {
  __bf16 h = (__bf16)f;
  return __builtin_bit_cast(unsigned short, h);
}
static __device__ __forceinline__ unsigned packbf(float a, float b) {
  return (unsigned)f2bf(a) | ((unsigned)f2bf(b) << 16);
}

// ---------------------------------------------------------------------------
// Convert 4 fp32 512x512 weights to bf16.
// ---------------------------------------------------------------------------
__global__ __launch_bounds__(256) void wconv_kernel(
    const float* __restrict__ w0, const float* __restrict__ w1,
    const float* __restrict__ w2, const float* __restrict__ w3,
    unsigned short* __restrict__ o0, unsigned short* __restrict__ o1,
    unsigned short* __restrict__ o2, unsigned short* __restrict__ o3) {
  int y = blockIdx.y;
  const float* src = (y == 0) ? w0 : (y == 1) ? w1 : (y == 2) ? w2 : w3;
  unsigned short* dst = (y == 0) ? o0 : (y == 1) ? o1 : (y == 2) ? o2 : o3;
  int idx = (blockIdx.x * 256 + threadIdx.x) * 8;
  float4 a = *(const float4*)&src[idx];
  float4 b = *(const float4*)&src[idx + 4];
  ushort4 p0, p1;
  p0.x = f2bf(a.x); p0.y = f2bf(a.y); p0.z = f2bf(a.z); p0.w = f2bf(a.w);
  p1.x = f2bf(b.x); p1.y = f2bf(b.y); p1.z = f2bf(b.z); p1.w = f2bf(b.w);
  *(ushort4*)&dst[idx] = p0;
  *(ushort4*)&dst[idx + 4] = p1;
}

// ---------------------------------------------------------------------------
// GroupNorm stats: one block per quarter-group. grid 256.
// ---------------------------------------------------------------------------
__global__ __launch_bounds__(256) void gn_stats_kernel(
    const float* __restrict__ x, float2* __restrict__ part) {
  int blk = blockIdx.x;
  const float4* __restrict__ x4 = (const float4*)(x + (size_t)blk * 16384);
  int t = threadIdx.x;
  float s = 0.f, ss = 0.f;
  #pragma unroll
  for (int i = 0; i < 16; ++i) {
    float4 v = x4[t + i * 256];
    s  += v.x + v.y + v.z + v.w;
    ss += v.x * v.x + v.y * v.y + v.z * v.z + v.w * v.w;
  }
  #pragma unroll
  for (int off = 32; off >= 1; off >>= 1) {
    s  += __shfl_down(s, off, 64);
    ss += __shfl_down(ss, off, 64);
  }
  __shared__ float rs[4], rss[4];
  int wid = t >> 6, lane = t & 63;
  if (lane == 0) { rs[wid] = s; rss[wid] = ss; }
  __syncthreads();
  if (t == 0) {
    float2 o;
    o.x = rs[0] + rs[1] + rs[2] + rs[3];
    o.y = rss[0] + rss[1] + rss[2] + rss[3];
    part[blk] = o;
  }
}

// ---------------------------------------------------------------------------
// Fused GroupNorm-apply + transpose: x fp32 [b][c][tok] -> xnT bf16 [b][tok][c].
// 64x64 tiles; grid (64, 8, 2), 256 thr. Normalization folded into tile load.
// ---------------------------------------------------------------------------
__global__ __launch_bounds__(256) void gn_norm_t_kernel(
    const float* __restrict__ x, const float* __restrict__ gamma,
    const float* __restrict__ beta, const float2* __restrict__ part,
    unsigned short* __restrict__ xnT) {
  __shared__ __align__(16) unsigned short lds[64 * 72];
  __shared__ float mu4[4], rs4[4];
  int b = blockIdx.z;
  int t0 = blockIdx.x * 64, c0 = blockIdx.y * 64;
  int t = threadIdx.x;
  if (t < 4) {
    int g = (c0 >> 4) + t;          // 4 groups span this 64-channel tile
    int gi = b * GROUPS + g;
    float2 p0 = part[gi * 4 + 0], p1 = part[gi * 4 + 1];
    float2 p2 = part[gi * 4 + 2], p3 = part[gi * 4 + 3];
    float S = p0.x + p1.x + p2.x + p3.x;
    float SS = p0.y + p1.y + p2.y + p3.y;
    const float inv_n = 1.0f / (float)(CPG * NN_TOK);
    float mu = S * inv_n;
    float var = SS * inv_n - mu * mu;
    mu4[t] = mu;
    rs4[t] = rsqrtf(var + EPS);
  }
  __syncthreads();
  const float* __restrict__ xb = x + (size_t)b * CC * NN_TOK;
  #pragma unroll
  for (int i = 0; i < 4; ++i) {
    int f = t + i * 256;            // 0..1023
    int row = f >> 4, c16 = f & 15; // row = channel-local, 16 float4/row
    int c = c0 + row;
    float ga = gamma[c] * rs4[row >> 4];
    float be = beta[c] - mu4[row >> 4] * ga;
    float4 v = *(const float4*)&xb[(size_t)c * NN_TOK + t0 + c16 * 4];
    ushort4 pk;
    pk.x = f2bf(v.x * ga + be); pk.y = f2bf(v.y * ga + be);
    pk.z = f2bf(v.z * ga + be); pk.w = f2bf(v.w * ga + be);
    *(ushort4*)&lds[row * 72 + c16 * 4] = pk;
  }
  __syncthreads();
  unsigned short* __restrict__ ob = xnT + (size_t)b * NN_TOK * CC;
  #pragma unroll
  for (int i = 0; i < 2; ++i) {
    int f = t + i * 256;
    int row = f >> 3, ch = f & 7;   // row = tok-local
    ushort4 a, b4;
    a.x  = lds[(ch * 8 + 0) * 72 + row];
    a.y  = lds[(ch * 8 + 1) * 72 + row];
    a.z  = lds[(ch * 8 + 2) * 72 + row];
    a.w  = lds[(ch * 8 + 3) * 72 + row];
    b4.x = lds[(ch * 8 + 4) * 72 + row];
    b4.y = lds[(ch * 8 + 5) * 72 + row];
    b4.z = lds[(ch * 8 + 6) * 72 + row];
    b4.w = lds[(ch * 8 + 7) * 72 + row];
    *(ushort4*)&ob[(size_t)(t0 + row) * CC + c0 + ch * 8] = a;
    *(ushort4*)&ob[(size_t)(t0 + row) * CC + c0 + ch * 8 + 4] = b4;
  }
}

// ---------------------------------------------------------------------------
// Fused Q/K/V MFMA GEMM (round-3 structure).
// ---------------------------------------------------------------------------
__global__ __launch_bounds__(256) void qkv_gemm_kernel(
    const unsigned short* __restrict__ xnT,
    const unsigned short* __restrict__ wqb, const unsigned short* __restrict__ wkb,
    const unsigned short* __restrict__ wvb,
    const float* __restrict__ bq, const float* __restrict__ bk,
    const float* __restrict__ bv,
    unsigned short* __restrict__ qT, unsigned short* __restrict__ kT,
    unsigned short* __restrict__ vB) {
  __shared__ __align__(16) unsigned short AsBs[2 * 128 * 72];
  unsigned short* As = AsBs;
  unsigned short* Bs = AsBs + 128 * 72;
  int b = blockIdx.z;
  int y = blockIdx.y;
  int which = y >> 2, yl = y & 3;
  const unsigned short* __restrict__ W =
      (which == 0) ? wqb : (which == 1) ? wkb : wvb;
  const float* __restrict__ bias = (which == 0) ? bq : (which == 1) ? bk : bv;
  int m0 = yl * 128;
  int n0 = blockIdx.x * 128;
  const unsigned short* __restrict__ Bsrc = xnT + (size_t)b * NN_TOK * CC;
  int t = threadIdx.x, w = t >> 6, lane = t & 63;
  int wm = (w >> 1) * 64, wn = (w & 1) * 64;
  int l15 = lane & 15, lq = lane >> 4;

  f32x4 acc[4][4];
  #pragma unroll
  for (int mt = 0; mt < 4; ++mt)
    #pragma unroll
    for (int nt = 0; nt < 4; ++nt) acc[mt][nt] = (f32x4){0.f, 0.f, 0.f, 0.f};

  for (int kc = 0; kc < CC; kc += 64) {
    __syncthreads();
    #pragma unroll
    for (int i = 0; i < 4; ++i) {
      int f = t + i * 256;
      int row = f >> 3, ch = f & 7;
      *(uint4*)&As[row * 72 + ch * 8] =
          *(const uint4*)&W[(size_t)(m0 + row) * CC + kc + ch * 8];
      *(uint4*)&Bs[row * 72 + ch * 8] =
          *(const uint4*)&Bsrc[(size_t)(n0 + row) * CC + kc + ch * 8];
    }
    __syncthreads();
    #pragma unroll
    for (int ks = 0; ks < 2; ++ks) {
      bf16x8 af[4], bfr[4];
      #pragma unroll
      for (int i = 0; i < 4; ++i) {
        af[i]  = *(const bf16x8*)&As[(wm + i * 16 + l15) * 72 + ks * 32 + lq * 8];
        bfr[i] = *(const bf16x8*)&Bs[(wn + i * 16 + l15) * 72 + ks * 32 + lq * 8];
      }
      #pragma unroll
      for (int mt = 0; mt < 4; ++mt)
        #pragma unroll
        for (int nt = 0; nt < 4; ++nt)
          acc[mt][nt] = __builtin_amdgcn_mfma_f32_16x16x32_bf16(
              af[mt], bfr[nt], acc[mt][nt], 0, 0, 0);
    }
  }
  __syncthreads();

  if (which < 2) {
    const float sc = (which == 0) ? 0.18033688011112043f : 1.0f; // 0.125*log2e
    unsigned short* __restrict__ dstT = (which == 0) ? qT : kT;
    unsigned short* buf = AsBs + w * 2304;
    int h = (m0 + wm) >> 6;
    const size_t hbase = (size_t)(b * HEADS + h) * NN_TOK;
    #pragma unroll
    for (int p = 0; p < 2; ++p) {
      #pragma unroll
      for (int mt = 0; mt < 4; ++mt) {
        float4 bv4 = *(const float4*)&bias[m0 + wm + mt * 16 + lq * 4];
        #pragma unroll
        for (int ntl = 0; ntl < 2; ++ntl) {
          int nt = p * 2 + ntl;
          f32x4 a = acc[mt][nt];
          ushort4 pk;
          pk.x = f2bf((a[0] + bv4.x) * sc);
          pk.y = f2bf((a[1] + bv4.y) * sc);
          pk.z = f2bf((a[2] + bv4.z) * sc);
          pk.w = f2bf((a[3] + bv4.w) * sc);
          *(ushort4*)&buf[(ntl * 16 + l15) * 72 + mt * 16 + lq * 4] = pk;
        }
      }
      #pragma unroll
      for (int it = 0; it < 4; ++it) {
        int idx = it * 64 + lane;
        int row = idx >> 3, ch = idx & 7;
        int tok = n0 + wn + p * 32 + row;
        *(uint4*)&dstT[(hbase + tok) * DHEAD + ch * 8] =
            *(const uint4*)&buf[row * 72 + ch * 8];
      }
    }
  } else {
    unsigned short* __restrict__ dst = vB + (size_t)b * HID * NN_TOK;
    #pragma unroll
    for (int mt = 0; mt < 4; ++mt) {
      float4 bv4 = *(const float4*)&bias[m0 + wm + mt * 16 + lq * 4];
      float bvr[4] = {bv4.x, bv4.y, bv4.z, bv4.w};
      #pragma unroll
      for (int nt = 0; nt < 4; ++nt) {
        int tok = n0 + wn + nt * 16 + l15;
        #pragma unroll
        for (int r = 0; r < 4; ++r) {
          int m = m0 + wm + mt * 16 + lq * 4 + r;
          dst[(size_t)m * NN_TOK + tok] = f2bf(acc[mt][nt][r] + bvr[r]);
        }
      }
    }
  }
}

// ---------------------------------------------------------------------------
// Out-proj MFMA GEMM: out = wo*ao^T + bo + x.
// ---------------------------------------------------------------------------
__global__ __launch_bounds__(256) void outproj_kernel(
    const unsigned short* __restrict__ aoT, const unsigned short* __restrict__ wob,
    const float* __restrict__ bo, const float* __restrict__ x,
    float* __restrict__ out) {
  __shared__ __align__(16) unsigned short AsBs[2 * 128 * 72];
  unsigned short* As = AsBs;
  unsigned short* Bs = AsBs + 128 * 72;
  int b = blockIdx.z;
  int m0 = blockIdx.y * 128;
  int n0 = blockIdx.x * 128;
  const unsigned short* __restrict__ Bsrc = aoT + (size_t)b * NN_TOK * HID;
  int t = threadIdx.x, w = t >> 6, lane = t & 63;
  int wm = (w >> 1) * 64, wn = (w & 1) * 64;
  int l15 = lane & 15, lq = lane >> 4;

  f32x4 acc[4][4];
  #pragma unroll
  for (int mt = 0; mt < 4; ++mt)
    #pragma unroll
    for (int nt = 0; nt < 4; ++nt) acc[mt][nt] = (f32x4){0.f, 0.f, 0.f, 0.f};

  for (int kc = 0; kc < HID; kc += 64) {
    __syncthreads();
    #pragma unroll
    for (int i = 0; i < 4; ++i) {
      int f = t + i * 256;
      int row = f >> 3, ch = f & 7;
      *(uint4*)&As[row * 72 + ch * 8] =
          *(const uint4*)&wob[(size_t)(m0 + row) * HID + kc + ch * 8];
      *(uint4*)&Bs[row * 72 + ch * 8] =
          *(const uint4*)&Bsrc[(size_t)(n0 + row) * HID + kc + ch * 8];
    }
    __syncthreads();
    #pragma unroll
    for (int ks = 0; ks < 2; ++ks) {
      bf16x8 af[4], bfr[4];
      #pragma unroll
      for (int i = 0; i < 4; ++i) {
        af[i]  = *(const bf16x8*)&As[(wm + i * 16 + l15) * 72 + ks * 32 + lq * 8];
        bfr[i] = *(const bf16x8*)&Bs[(wn + i * 16 + l15) * 72 + ks * 32 + lq * 8];
      }
      #pragma unroll
      for (int mt = 0; mt < 4; ++mt)
        #pragma unroll
        for (int nt = 0; nt < 4; ++nt)
          acc[mt][nt] = __builtin_amdgcn_mfma_f32_16x16x32_bf16(
              af[mt], bfr[nt], acc[mt][nt], 0, 0, 0);
    }
  }

  const float* __restrict__ xb = x + (size_t)b * CC * NN_TOK;
  float* __restrict__ ob = out + (size_t)b * CC * NN_TOK;
  #pragma unroll
  for (int mt = 0; mt < 4; ++mt) {
    float4 bv4 = *(const float4*)&bo[m0 + wm + mt * 16 + lq * 4];
    float bvr[4] = {bv4.x, bv4.y, bv4.z, bv4.w};
    #pragma unroll
    for (int nt = 0; nt < 4; ++nt) {
      int tok = n0 + wn + nt * 16 + l15;
      #pragma unroll
      for (int r = 0; r < 4; ++r) {
        int m = m0 + wm + mt * 16 + lq * 4 + r;
        size_t off = (size_t)m * NN_TOK + tok;
        ob[off] = acc[mt][nt][r] + bvr[r] + xb[off];
      }
    }
  }
}

// ---------------------------------------------------------------------------
// MFMA flash attention, round 8: exact round-5 geometry (512 thr = 4 i-strips
// x 2 j-parities, 128 j staged/iter, 4 waves/SIMD) + in-register P repack
// from r6 (one __shfl_xor(32) pair per K-step; adds only dw[16] regs, stays
// under the 128-reg cap of __launch_bounds__(512,4) — r7's spill came from
// the i-width-64 variant's ~190 regs, not the repack itself).
// Plain stride-72 tiles. No-shift exp2 softmax. No P LDS buffer.
// ---------------------------------------------------------------------------
__global__ __launch_bounds__(512, 4) void attn_mfma_kernel(
    const unsigned short* __restrict__ qT, const unsigned short* __restrict__ kT,
    const unsigned short* __restrict__ vv, unsigned short* __restrict__ aoT) {
  __shared__ __align__(16) unsigned short kv[4 * 64 * 72]; // 2 K + 2 V tiles
  __shared__ __align__(16) unsigned short st[4 * 32 * 72]; // epilogue stage
  __shared__ float lbuf[128];
  unsigned short* ks2 = kv;
  unsigned short* vs2 = kv + 2 * 64 * 72;
  int bh = blockIdx.y;
  int b = bh >> 3, h = bh & 7;
  int i0 = blockIdx.x * 128;
  const size_t hb = (size_t)bh * NN_TOK;
  const unsigned short* __restrict__ qtg = qT + hb * DHEAD;
  const unsigned short* __restrict__ ktg = kT + hb * DHEAD;
  const unsigned short* __restrict__ vg  = vv + hb * DHEAD;
  int t = threadIdx.x;
  int w = t >> 6, lane = t & 63, l31 = lane & 31, q1 = lane >> 5;
  int strip = w & 3, parity = w >> 2;
  int iw = i0 + strip * 32;

  bf16x8 qf[4];
  #pragma unroll
  for (int s = 0; s < 4; ++s)
    qf[s] = *(const bf16x8*)&qtg[(size_t)(iw + l31) * DHEAD + s * 16 + q1 * 8];

  f32x16 o0 = {0,0,0,0,0,0,0,0,0,0,0,0,0,0,0,0};
  f32x16 o1 = {0,0,0,0,0,0,0,0,0,0,0,0,0,0,0,0};
  float lrun = 0.f;
  const unsigned short* __restrict__ ksw = ks2 + parity * 64 * 72;
  const unsigned short* __restrict__ vsw = vs2 + parity * 64 * 72;

  for (int rt = 0; rt < NN_TOK / 128; ++rt) {
    int j0 = rt * 128;
    __syncthreads();
    #pragma unroll
    for (int i = 0; i < 2; ++i) {
      int f = t + i * 512;                 // 0..1023
      int tile = f >> 9, rr = (f >> 3) & 63, ch = f & 7;
      *(uint4*)&ks2[(tile * 64 + rr) * 72 + ch * 8] =
          *(const uint4*)&ktg[(size_t)(j0 + tile * 64 + rr) * DHEAD + ch * 8];
      *(uint4*)&vs2[(tile * 64 + rr) * 72 + ch * 8] =
          *(const uint4*)&vg[(size_t)rr * NN_TOK + j0 + tile * 64 + ch * 8];
    }
    __syncthreads();

    // S^T[j][i] on this wave's 64-j parity tile
    f32x16 s0 = {0,0,0,0,0,0,0,0,0,0,0,0,0,0,0,0};
    f32x16 s1 = {0,0,0,0,0,0,0,0,0,0,0,0,0,0,0,0};
    #pragma unroll
    for (int s = 0; s < 4; ++s) {
      int slot = s * 16 + q1 * 8;
      bf16x8 a0 = *(const bf16x8*)&ksw[l31 * 72 + slot];
      bf16x8 a1 = *(const bf16x8*)&ksw[(32 + l31) * 72 + slot];
      s0 = __builtin_amdgcn_mfma_f32_32x32x16_bf16(a0, qf[s], s0, 0, 0, 0);
      s1 = __builtin_amdgcn_mfma_f32_32x32x16_bf16(a1, qf[s], s1, 0, 0, 0);
    }

    // exp2 (no shift) + pack to dwords in j-order
    unsigned dw[16];
    float psum = 0.f;
    #pragma unroll
    for (int m = 0; m < 8; ++m) {
      float pa = __builtin_amdgcn_exp2f(s0[2 * m]);
      float pb = __builtin_amdgcn_exp2f(s0[2 * m + 1]);
      psum += pa + pb;
      dw[m] = packbf(pa, pb);
    }
    #pragma unroll
    for (int m = 0; m < 8; ++m) {
      float pa = __builtin_amdgcn_exp2f(s1[2 * m]);
      float pb = __builtin_amdgcn_exp2f(s1[2 * m + 1]);
      psum += pa + pb;
      dw[8 + m] = packbf(pa, pb);
    }
    psum += __shfl_xor(psum, 32);
    lrun += psum;

    // PV: P B-fragments built in-register (r6-verified repack)
    #pragma unroll
    for (int s = 0; s < 4; ++s) {
      int slot = s * 16 + q1 * 8;
      bf16x8 va0 = *(const bf16x8*)&vsw[l31 * 72 + slot];
      bf16x8 va1 = *(const bf16x8*)&vsw[(32 + l31) * 72 + slot];
      int base = (s >> 1) * 8 + (s & 1) * 4;
      unsigned m0 = dw[base], m1 = dw[base + 1];
      unsigned m2 = dw[base + 2], m3 = dw[base + 3];
      unsigned y0 = q1 ? m0 : m2;
      unsigned y1 = q1 ? m1 : m3;
      unsigned z0 = (unsigned)__shfl_xor((int)y0, 32);
      unsigned z1 = (unsigned)__shfl_xor((int)y1, 32);
      uint4 fr;
      fr.x = q1 ? z0 : m0;
      fr.y = q1 ? z1 : m1;
      fr.z = q1 ? m2 : z0;
      fr.w = q1 ? m3 : z1;
      bf16x8 pb = __builtin_bit_cast(bf16x8, fr);
      o0 = __builtin_amdgcn_mfma_f32_32x32x16_bf16(va0, pb, o0, 0, 0, 0);
      o1 = __builtin_amdgcn_mfma_f32_32x32x16_bf16(va1, pb, o1, 0, 0, 0);
    }
  }

  // combine parity partials through LDS
  __syncthreads();
  float* obuf = (float*)kv;            // [strip][d 64][i 32], 32 KB overlay
  if (parity == 1) {
    #pragma unroll
    for (int dm = 0; dm < 2; ++dm)
      #pragma unroll
      for (int r = 0; r < 16; ++r) {
        int d = dm * 32 + (r & 3) + 8 * (r >> 2) + 4 * q1;
        obuf[strip * 2048 + d * 32 + l31] = (dm == 0) ? o0[r] : o1[r];
      }
    if (q1 == 0) lbuf[strip * 32 + l31] = lrun;
  }
  __syncthreads();
  if (parity == 0) {
    lrun += lbuf[strip * 32 + l31];
    float inv = 1.0f / lrun;
    unsigned short* stw = st + strip * 2304;   // [32 i][72]
    #pragma unroll
    for (int dm = 0; dm < 2; ++dm) {
      #pragma unroll
      for (int g = 0; g < 4; ++g) {
        float v[4];
        #pragma unroll
        for (int i = 0; i < 4; ++i) {
          int r = 4 * g + i;
          int d = dm * 32 + i + 8 * g + 4 * q1;
          float part = obuf[strip * 2048 + d * 32 + l31];
          v[i] = (((dm == 0) ? o0[r] : o1[r]) + part) * inv;
        }
        ushort4 pk;
        pk.x = f2bf(v[0]); pk.y = f2bf(v[1]); pk.z = f2bf(v[2]); pk.w = f2bf(v[3]);
        *(ushort4*)&stw[l31 * 72 + dm * 32 + g * 8 + q1 * 4] = pk;
      }
    }
    const size_t obase = (size_t)b * NN_TOK;
    #pragma unroll
    for (int it = 0; it < 4; ++it) {
      int idx = it * 64 + lane;
      int row = idx >> 3, ch = idx & 7;
      int tok = iw + row;
      *(uint4*)&aoT[(obase + tok) * HID + h * DHEAD + ch * 8] =
          *(const uint4*)&stw[row * 72 + ch * 8];
    }
  }
}

// ---------------------------------------------------------------------------
extern "C" void kernel_launch(void* const* d_in, const int* in_sizes, int n_in,
                              void* d_out, int out_size, void* d_ws, size_t ws_size,
                              hipStream_t stream) {
  const float* x     = (const float*)d_in[0];
  const float* gamma = (const float*)d_in[1];
  const float* beta  = (const float*)d_in[2];
  const float* wq    = (const float*)d_in[3];
  const float* bq    = (const float*)d_in[4];
  const float* wk    = (const float*)d_in[5];
  const float* bk    = (const float*)d_in[6];
  const float* wv    = (const float*)d_in[7];
  const float* bv    = (const float*)d_in[8];
  const float* wo    = (const float*)d_in[9];
  const float* bo    = (const float*)d_in[10];
  float* out = (float*)d_out;

  const size_t SZ = (size_t)BB * CC * NN_TOK;
  const size_t WZ = (size_t)CC * HID;
  unsigned short* xnT = (unsigned short*)d_ws;      // bf16 [b][tok][c]
  unsigned short* qT  = xnT + SZ;                   // bf16 [b,h,tok,d]
  unsigned short* kT  = qT + SZ;
  unsigned short* vB  = kT + SZ;                    // bf16 [b][c][tok]
  unsigned short* aoT = vB + SZ;                    // bf16 [b][tok][hid]
  unsigned short* wqb = aoT + SZ;
  unsigned short* wkb = wqb + WZ;
  unsigned short* wvb = wkb + WZ;
  unsigned short* wob = wvb + WZ;
  float2* gnpart = (float2*)(wob + WZ);

  wconv_kernel<<<dim3(128, 4), dim3(256), 0, stream>>>(
      wq, wk, wv, wo, wqb, wkb, wvb, wob);

  gn_stats_kernel<<<dim3(256), dim3(256), 0, stream>>>(x, gnpart);
  gn_norm_t_kernel<<<dim3(NN_TOK / 64, CC / 64, BB), dim3(256), 0, stream>>>(
      x, gamma, beta, gnpart, xnT);

  qkv_gemm_kernel<<<dim3(NN_TOK / 128, 12, BB), dim3(256), 0, stream>>>(
      xnT, wqb, wkb, wvb, bq, bk, bv, qT, kT, vB);

  attn_mfma_kernel<<<dim3(NN_TOK / 128, BB * HEADS), dim3(512), 0, stream>>>(
      qT, kT, vB, aoT);

  outproj_kernel<<<dim3(NN_TOK / 128, CC / 128, BB), dim3(256), 0, stream>>>(
      aoT, wob, bo, x, out);
}

// Round 9
// 214.256 us; speedup vs baseline: 3.1760x; 1.0511x over previous
//
#include <hip/hip_runtime.h>
#include <math.h>

#define BB      2
#define CC      512
#define NN_TOK  4096
#define HEADS   8
#define DHEAD   64
#define HID     512
#define GROUPS  32
#define CPG     (CC / GROUPS)
#define EPS     1e-5f

typedef __bf16 bf16x8 __attribute__((ext_vector_type(8)));
typedef float  f32x4  __attribute__((ext_vector_type(4)));
typedef float  f32x16 __attribute__((ext_vector_type(16)));

static __device__ __forceinline__ unsigned short f2bf(float f) {
  __bf16 h = (__bf16)f;
  return __builtin_bit_cast(unsigned short, h);
}
static __device__ __forceinline__ unsigned packbf(float a, float b) {
  return (unsigned)f2bf(a) | ((unsigned)f2bf(b) << 16);
}

// ---------------------------------------------------------------------------
// Convert 4 fp32 512x512 weights to bf16.
// ---------------------------------------------------------------------------
__global__ __launch_bounds__(256) void wconv_kernel(
    const float* __restrict__ w0, const float* __restrict__ w1,
    const float* __restrict__ w2, const float* __restrict__ w3,
    unsigned short* __restrict__ o0, unsigned short* __restrict__ o1,
    unsigned short* __restrict__ o2, unsigned short* __restrict__ o3) {
  int y = blockIdx.y;
  const float* src = (y == 0) ? w0 : (y == 1) ? w1 : (y == 2) ? w2 : w3;
  unsigned short* dst = (y == 0) ? o0 : (y == 1) ? o1 : (y == 2) ? o2 : o3;
  int idx = (blockIdx.x * 256 + threadIdx.x) * 8;
  float4 a = *(const float4*)&src[idx];
  float4 b = *(const float4*)&src[idx + 4];
  ushort4 p0, p1;
  p0.x = f2bf(a.x); p0.y = f2bf(a.y); p0.z = f2bf(a.z); p0.w = f2bf(a.w);
  p1.x = f2bf(b.x); p1.y = f2bf(b.y); p1.z = f2bf(b.z); p1.w = f2bf(b.w);
  *(ushort4*)&dst[idx] = p0;
  *(ushort4*)&dst[idx + 4] = p1;
}

// ---------------------------------------------------------------------------
// GroupNorm stats: one block per quarter-group. grid 256.
// ---------------------------------------------------------------------------
__global__ __launch_bounds__(256) void gn_stats_kernel(
    const float* __restrict__ x, float2* __restrict__ part) {
  int blk = blockIdx.x;
  const float4* __restrict__ x4 = (const float4*)(x + (size_t)blk * 16384);
  int t = threadIdx.x;
  float s = 0.f, ss = 0.f;
  #pragma unroll
  for (int i = 0; i < 16; ++i) {
    float4 v = x4[t + i * 256];
    s  += v.x + v.y + v.z + v.w;
    ss += v.x * v.x + v.y * v.y + v.z * v.z + v.w * v.w;
  }
  #pragma unroll
  for (int off = 32; off >= 1; off >>= 1) {
    s  += __shfl_down(s, off, 64);
    ss += __shfl_down(ss, off, 64);
  }
  __shared__ float rs[4], rss[4];
  int wid = t >> 6, lane = t & 63;
  if (lane == 0) { rs[wid] = s; rss[wid] = ss; }
  __syncthreads();
  if (t == 0) {
    float2 o;
    o.x = rs[0] + rs[1] + rs[2] + rs[3];
    o.y = rss[0] + rss[1] + rss[2] + rss[3];
    part[blk] = o;
  }
}

// ---------------------------------------------------------------------------
// Fused GroupNorm-apply + transpose: x fp32 [b][c][tok] -> xnT bf16 [b][tok][c].
// ---------------------------------------------------------------------------
__global__ __launch_bounds__(256) void gn_norm_t_kernel(
    const float* __restrict__ x, const float* __restrict__ gamma,
    const float* __restrict__ beta, const float2* __restrict__ part,
    unsigned short* __restrict__ xnT) {
  __shared__ __align__(16) unsigned short lds[64 * 72];
  __shared__ float mu4[4], rs4[4];
  int b = blockIdx.z;
  int t0 = blockIdx.x * 64, c0 = blockIdx.y * 64;
  int t = threadIdx.x;
  if (t < 4) {
    int g = (c0 >> 4) + t;
    int gi = b * GROUPS + g;
    float2 p0 = part[gi * 4 + 0], p1 = part[gi * 4 + 1];
    float2 p2 = part[gi * 4 + 2], p3 = part[gi * 4 + 3];
    float S = p0.x + p1.x + p2.x + p3.x;
    float SS = p0.y + p1.y + p2.y + p3.y;
    const float inv_n = 1.0f / (float)(CPG * NN_TOK);
    float mu = S * inv_n;
    float var = SS * inv_n - mu * mu;
    mu4[t] = mu;
    rs4[t] = rsqrtf(var + EPS);
  }
  __syncthreads();
  const float* __restrict__ xb = x + (size_t)b * CC * NN_TOK;
  #pragma unroll
  for (int i = 0; i < 4; ++i) {
    int f = t + i * 256;
    int row = f >> 4, c16 = f & 15;
    int c = c0 + row;
    float ga = gamma[c] * rs4[row >> 4];
    float be = beta[c] - mu4[row >> 4] * ga;
    float4 v = *(const float4*)&xb[(size_t)c * NN_TOK + t0 + c16 * 4];
    ushort4 pk;
    pk.x = f2bf(v.x * ga + be); pk.y = f2bf(v.y * ga + be);
    pk.z = f2bf(v.z * ga + be); pk.w = f2bf(v.w * ga + be);
    *(ushort4*)&lds[row * 72 + c16 * 4] = pk;
  }
  __syncthreads();
  unsigned short* __restrict__ ob = xnT + (size_t)b * NN_TOK * CC;
  #pragma unroll
  for (int i = 0; i < 2; ++i) {
    int f = t + i * 256;
    int row = f >> 3, ch = f & 7;
    ushort4 a, b4;
    a.x  = lds[(ch * 8 + 0) * 72 + row];
    a.y  = lds[(ch * 8 + 1) * 72 + row];
    a.z  = lds[(ch * 8 + 2) * 72 + row];
    a.w  = lds[(ch * 8 + 3) * 72 + row];
    b4.x = lds[(ch * 8 + 4) * 72 + row];
    b4.y = lds[(ch * 8 + 5) * 72 + row];
    b4.z = lds[(ch * 8 + 6) * 72 + row];
    b4.w = lds[(ch * 8 + 7) * 72 + row];
    *(ushort4*)&ob[(size_t)(t0 + row) * CC + c0 + ch * 8] = a;
    *(ushort4*)&ob[(size_t)(t0 + row) * CC + c0 + ch * 8 + 4] = b4;
  }
}

// ---------------------------------------------------------------------------
// Fused Q/K/V MFMA GEMM. launch_bounds(256,3): all 768 blocks co-resident
// (3 blocks/CU), removing the 256-block tail round.
// ---------------------------------------------------------------------------
__global__ __launch_bounds__(256, 3) void qkv_gemm_kernel(
    const unsigned short* __restrict__ xnT,
    const unsigned short* __restrict__ wqb, const unsigned short* __restrict__ wkb,
    const unsigned short* __restrict__ wvb,
    const float* __restrict__ bq, const float* __restrict__ bk,
    const float* __restrict__ bv,
    unsigned short* __restrict__ qT, unsigned short* __restrict__ kT,
    unsigned short* __restrict__ vB) {
  __shared__ __align__(16) unsigned short AsBs[2 * 128 * 72];
  unsigned short* As = AsBs;
  unsigned short* Bs = AsBs + 128 * 72;
  int b = blockIdx.z;
  int y = blockIdx.y;
  int which = y >> 2, yl = y & 3;
  const unsigned short* __restrict__ W =
      (which == 0) ? wqb : (which == 1) ? wkb : wvb;
  const float* __restrict__ bias = (which == 0) ? bq : (which == 1) ? bk : bv;
  int m0 = yl * 128;
  int n0 = blockIdx.x * 128;
  const unsigned short* __restrict__ Bsrc = xnT + (size_t)b * NN_TOK * CC;
  int t = threadIdx.x, w = t >> 6, lane = t & 63;
  int wm = (w >> 1) * 64, wn = (w & 1) * 64;
  int l15 = lane & 15, lq = lane >> 4;

  f32x4 acc[4][4];
  #pragma unroll
  for (int mt = 0; mt < 4; ++mt)
    #pragma unroll
    for (int nt = 0; nt < 4; ++nt) acc[mt][nt] = (f32x4){0.f, 0.f, 0.f, 0.f};

  for (int kc = 0; kc < CC; kc += 64) {
    __syncthreads();
    #pragma unroll
    for (int i = 0; i < 4; ++i) {
      int f = t + i * 256;
      int row = f >> 3, ch = f & 7;
      *(uint4*)&As[row * 72 + ch * 8] =
          *(const uint4*)&W[(size_t)(m0 + row) * CC + kc + ch * 8];
      *(uint4*)&Bs[row * 72 + ch * 8] =
          *(const uint4*)&Bsrc[(size_t)(n0 + row) * CC + kc + ch * 8];
    }
    __syncthreads();
    #pragma unroll
    for (int ks = 0; ks < 2; ++ks) {
      bf16x8 af[4], bfr[4];
      #pragma unroll
      for (int i = 0; i < 4; ++i) {
        af[i]  = *(const bf16x8*)&As[(wm + i * 16 + l15) * 72 + ks * 32 + lq * 8];
        bfr[i] = *(const bf16x8*)&Bs[(wn + i * 16 + l15) * 72 + ks * 32 + lq * 8];
      }
      #pragma unroll
      for (int mt = 0; mt < 4; ++mt)
        #pragma unroll
        for (int nt = 0; nt < 4; ++nt)
          acc[mt][nt] = __builtin_amdgcn_mfma_f32_16x16x32_bf16(
              af[mt], bfr[nt], acc[mt][nt], 0, 0, 0);
    }
  }
  __syncthreads();

  if (which < 2) {
    const float sc = (which == 0) ? 0.18033688011112043f : 1.0f; // 0.125*log2e
    unsigned short* __restrict__ dstT = (which == 0) ? qT : kT;
    unsigned short* buf = AsBs + w * 2304;
    int h = (m0 + wm) >> 6;
    const size_t hbase = (size_t)(b * HEADS + h) * NN_TOK;
    #pragma unroll
    for (int p = 0; p < 2; ++p) {
      #pragma unroll
      for (int mt = 0; mt < 4; ++mt) {
        float4 bv4 = *(const float4*)&bias[m0 + wm + mt * 16 + lq * 4];
        #pragma unroll
        for (int ntl = 0; ntl < 2; ++ntl) {
          int nt = p * 2 + ntl;
          f32x4 a = acc[mt][nt];
          ushort4 pk;
          pk.x = f2bf((a[0] + bv4.x) * sc);
          pk.y = f2bf((a[1] + bv4.y) * sc);
          pk.z = f2bf((a[2] + bv4.z) * sc);
          pk.w = f2bf((a[3] + bv4.w) * sc);
          *(ushort4*)&buf[(ntl * 16 + l15) * 72 + mt * 16 + lq * 4] = pk;
        }
      }
      #pragma unroll
      for (int it = 0; it < 4; ++it) {
        int idx = it * 64 + lane;
        int row = idx >> 3, ch = idx & 7;
        int tok = n0 + wn + p * 32 + row;
        *(uint4*)&dstT[(hbase + tok) * DHEAD + ch * 8] =
            *(const uint4*)&buf[row * 72 + ch * 8];
      }
    }
  } else {
    unsigned short* __restrict__ dst = vB + (size_t)b * HID * NN_TOK;
    #pragma unroll
    for (int mt = 0; mt < 4; ++mt) {
      float4 bv4 = *(const float4*)&bias[m0 + wm + mt * 16 + lq * 4];
      float bvr[4] = {bv4.x, bv4.y, bv4.z, bv4.w};
      #pragma unroll
      for (int nt = 0; nt < 4; ++nt) {
        int tok = n0 + wn + nt * 16 + l15;
        #pragma unroll
        for (int r = 0; r < 4; ++r) {
          int m = m0 + wm + mt * 16 + lq * 4 + r;
          dst[(size_t)m * NN_TOK + tok] = f2bf(acc[mt][nt][r] + bvr[r]);
        }
      }
    }
  }
}

// ---------------------------------------------------------------------------
// Out-proj MFMA GEMM, retiled 128m x 64n: grid (64,4,2)=512 blocks ->
// 2 blocks/CU (was 256 blocks = 1/CU, occupancy-starved).
// ---------------------------------------------------------------------------
__global__ __launch_bounds__(256) void outproj_kernel(
    const unsigned short* __restrict__ aoT, const unsigned short* __restrict__ wob,
    const float* __restrict__ bo, const float* __restrict__ x,
    float* __restrict__ out) {
  __shared__ __align__(16) unsigned short As[128 * 72];
  __shared__ __align__(16) unsigned short Bs[64 * 72];
  int b = blockIdx.z;
  int m0 = blockIdx.y * 128;
  int n0 = blockIdx.x * 64;
  const unsigned short* __restrict__ Bsrc = aoT + (size_t)b * NN_TOK * HID;
  int t = threadIdx.x, w = t >> 6, lane = t & 63;
  int wm = (w & 1) * 64, wn = (w >> 1) * 32;
  int l15 = lane & 15, lq = lane >> 4;

  f32x4 acc[4][2];
  #pragma unroll
  for (int mt = 0; mt < 4; ++mt)
    #pragma unroll
    for (int nt = 0; nt < 2; ++nt) acc[mt][nt] = (f32x4){0.f, 0.f, 0.f, 0.f};

  for (int kc = 0; kc < HID; kc += 64) {
    __syncthreads();
    #pragma unroll
    for (int i = 0; i < 4; ++i) {
      int f = t + i * 256;
      int row = f >> 3, ch = f & 7;
      *(uint4*)&As[row * 72 + ch * 8] =
          *(const uint4*)&wob[(size_t)(m0 + row) * HID + kc + ch * 8];
    }
    #pragma unroll
    for (int i = 0; i < 2; ++i) {
      int f = t + i * 256;
      int row = f >> 3, ch = f & 7;
      *(uint4*)&Bs[row * 72 + ch * 8] =
          *(const uint4*)&Bsrc[(size_t)(n0 + row) * HID + kc + ch * 8];
    }
    __syncthreads();
    #pragma unroll
    for (int ks = 0; ks < 2; ++ks) {
      bf16x8 af[4], bfr[2];
      #pragma unroll
      for (int i = 0; i < 4; ++i)
        af[i] = *(const bf16x8*)&As[(wm + i * 16 + l15) * 72 + ks * 32 + lq * 8];
      #pragma unroll
      for (int i = 0; i < 2; ++i)
        bfr[i] = *(const bf16x8*)&Bs[(wn + i * 16 + l15) * 72 + ks * 32 + lq * 8];
      #pragma unroll
      for (int mt = 0; mt < 4; ++mt)
        #pragma unroll
        for (int nt = 0; nt < 2; ++nt)
          acc[mt][nt] = __builtin_amdgcn_mfma_f32_16x16x32_bf16(
              af[mt], bfr[nt], acc[mt][nt], 0, 0, 0);
    }
  }

  const float* __restrict__ xb = x + (size_t)b * CC * NN_TOK;
  float* __restrict__ ob = out + (size_t)b * CC * NN_TOK;
  #pragma unroll
  for (int mt = 0; mt < 4; ++mt) {
    float4 bv4 = *(const float4*)&bo[m0 + wm + mt * 16 + lq * 4];
    float bvr[4] = {bv4.x, bv4.y, bv4.z, bv4.w};
    #pragma unroll
    for (int nt = 0; nt < 2; ++nt) {
      int tok = n0 + wn + nt * 16 + l15;
      #pragma unroll
      for (int r = 0; r < 4; ++r) {
        int m = m0 + wm + mt * 16 + lq * 4 + r;
        size_t off = (size_t)m * NN_TOK + tok;
        ob[off] = acc[mt][nt][r] + bvr[r] + xb[off];
      }
    }
  }
}

// ---------------------------------------------------------------------------
// MFMA flash attention, round 9: r8 compute body + DOUBLE-BUFFERED K/V
// staging. One barrier per iter; next tile's global loads issue before the
// current tile's compute so they overlap the 16 MFMAs + softmax (prefetch
// pattern the 2-barrier loop couldn't express). LDS 73.7 KB, 2 blocks/CU.
// ---------------------------------------------------------------------------
__global__ __launch_bounds__(512, 4) void attn_mfma_kernel(
    const unsigned short* __restrict__ qT, const unsigned short* __restrict__ kT,
    const unsigned short* __restrict__ vv, unsigned short* __restrict__ aoT) {
  __shared__ __align__(16) unsigned short kv[2][4 * 64 * 72]; // dbuf: 2K+2V tiles
  __shared__ float lbuf[128];
  int bh = blockIdx.y;
  int b = bh >> 3, h = bh & 7;
  int i0 = blockIdx.x * 128;
  const size_t hb = (size_t)bh * NN_TOK;
  const unsigned short* __restrict__ qtg = qT + hb * DHEAD;
  const unsigned short* __restrict__ ktg = kT + hb * DHEAD;
  const unsigned short* __restrict__ vg  = vv + hb * DHEAD;
  int t = threadIdx.x;
  int w = t >> 6, lane = t & 63, l31 = lane & 31, q1 = lane >> 5;
  int strip = w & 3, parity = w >> 2;
  int iw = i0 + strip * 32;

  bf16x8 qf[4];
  #pragma unroll
  for (int s = 0; s < 4; ++s)
    qf[s] = *(const bf16x8*)&qtg[(size_t)(iw + l31) * DHEAD + s * 16 + q1 * 8];

  f32x16 o0 = {0,0,0,0,0,0,0,0,0,0,0,0,0,0,0,0};
  f32x16 o1 = {0,0,0,0,0,0,0,0,0,0,0,0,0,0,0,0};
  float lrun = 0.f;

  auto stage = [&](int rt) {
    int j0 = rt * 128;
    unsigned short* ks2 = kv[rt & 1];
    unsigned short* vs2 = kv[rt & 1] + 2 * 64 * 72;
    #pragma unroll
    for (int i = 0; i < 2; ++i) {
      int f = t + i * 512;                 // 0..1023
      int tile = f >> 9, rr = (f >> 3) & 63, ch = f & 7;
      *(uint4*)&ks2[(tile * 64 + rr) * 72 + ch * 8] =
          *(const uint4*)&ktg[(size_t)(j0 + tile * 64 + rr) * DHEAD + ch * 8];
      *(uint4*)&vs2[(tile * 64 + rr) * 72 + ch * 8] =
          *(const uint4*)&vg[(size_t)rr * NN_TOK + j0 + tile * 64 + ch * 8];
    }
  };

  stage(0);
  for (int rt = 0; rt < NN_TOK / 128; ++rt) {
    __syncthreads();   // buf[rt&1] visible; prior consumers of buf[(rt+1)&1] done
    if (rt + 1 < NN_TOK / 128) stage(rt + 1);
    const unsigned short* __restrict__ ksw = kv[rt & 1] + parity * 64 * 72;
    const unsigned short* __restrict__ vsw = kv[rt & 1] + (2 + parity) * 64 * 72;

    // S^T[j][i] on this wave's 64-j parity tile
    f32x16 s0 = {0,0,0,0,0,0,0,0,0,0,0,0,0,0,0,0};
    f32x16 s1 = {0,0,0,0,0,0,0,0,0,0,0,0,0,0,0,0};
    #pragma unroll
    for (int s = 0; s < 4; ++s) {
      int slot = s * 16 + q1 * 8;
      bf16x8 a0 = *(const bf16x8*)&ksw[l31 * 72 + slot];
      bf16x8 a1 = *(const bf16x8*)&ksw[(32 + l31) * 72 + slot];
      s0 = __builtin_amdgcn_mfma_f32_32x32x16_bf16(a0, qf[s], s0, 0, 0, 0);
      s1 = __builtin_amdgcn_mfma_f32_32x32x16_bf16(a1, qf[s], s1, 0, 0, 0);
    }

    // exp2 (no shift) + pack to dwords in j-order
    unsigned dw[16];
    float psum = 0.f;
    #pragma unroll
    for (int m = 0; m < 8; ++m) {
      float pa = __builtin_amdgcn_exp2f(s0[2 * m]);
      float pb = __builtin_amdgcn_exp2f(s0[2 * m + 1]);
      psum += pa + pb;
      dw[m] = packbf(pa, pb);
    }
    #pragma unroll
    for (int m = 0; m < 8; ++m) {
      float pa = __builtin_amdgcn_exp2f(s1[2 * m]);
      float pb = __builtin_amdgcn_exp2f(s1[2 * m + 1]);
      psum += pa + pb;
      dw[8 + m] = packbf(pa, pb);
    }
    psum += __shfl_xor(psum, 32);
    lrun += psum;

    // PV: P B-fragments built in-register (r6-verified repack)
    #pragma unroll
    for (int s = 0; s < 4; ++s) {
      int slot = s * 16 + q1 * 8;
      bf16x8 va0 = *(const bf16x8*)&vsw[l31 * 72 + slot];
      bf16x8 va1 = *(const bf16x8*)&vsw[(32 + l31) * 72 + slot];
      int base = (s >> 1) * 8 + (s & 1) * 4;
      unsigned m0 = dw[base], m1 = dw[base + 1];
      unsigned m2 = dw[base + 2], m3 = dw[base + 3];
      unsigned y0 = q1 ? m0 : m2;
      unsigned y1 = q1 ? m1 : m3;
      unsigned z0 = (unsigned)__shfl_xor((int)y0, 32);
      unsigned z1 = (unsigned)__shfl_xor((int)y1, 32);
      uint4 fr;
      fr.x = q1 ? z0 : m0;
      fr.y = q1 ? z1 : m1;
      fr.z = q1 ? m2 : z0;
      fr.w = q1 ? m3 : z1;
      bf16x8 pb = __builtin_bit_cast(bf16x8, fr);
      o0 = __builtin_amdgcn_mfma_f32_32x32x16_bf16(va0, pb, o0, 0, 0, 0);
      o1 = __builtin_amdgcn_mfma_f32_32x32x16_bf16(va1, pb, o1, 0, 0, 0);
    }
  }

  // combine parity partials through LDS (obuf overlays kv[1], st overlays kv[0])
  __syncthreads();
  float* obuf = (float*)kv[1];         // [strip][d 64][i 32], 32 KB
  unsigned short* st = kv[0];          // [strip][32 i][72]
  if (parity == 1) {
    #pragma unroll
    for (int dm = 0; dm < 2; ++dm)
      #pragma unroll
      for (int r = 0; r < 16; ++r) {
        int d = dm * 32 + (r & 3) + 8 * (r >> 2) + 4 * q1;
        obuf[strip * 2048 + d * 32 + l31] = (dm == 0) ? o0[r] : o1[r];
      }
    if (q1 == 0) lbuf[strip * 32 + l31] = lrun;
  }
  __syncthreads();
  if (parity == 0) {
    lrun += lbuf[strip * 32 + l31];
    float inv = 1.0f / lrun;
    unsigned short* stw = st + strip * 2304;
    #pragma unroll
    for (int dm = 0; dm < 2; ++dm) {
      #pragma unroll
      for (int g = 0; g < 4; ++g) {
        float v[4];
        #pragma unroll
        for (int i = 0; i < 4; ++i) {
          int r = 4 * g + i;
          int d = dm * 32 + i + 8 * g + 4 * q1;
          float part = obuf[strip * 2048 + d * 32 + l31];
          v[i] = (((dm == 0) ? o0[r] : o1[r]) + part) * inv;
        }
        ushort4 pk;
        pk.x = f2bf(v[0]); pk.y = f2bf(v[1]); pk.z = f2bf(v[2]); pk.w = f2bf(v[3]);
        *(ushort4*)&stw[l31 * 72 + dm * 32 + g * 8 + q1 * 4] = pk;
      }
    }
    const size_t obase = (size_t)b * NN_TOK;
    #pragma unroll
    for (int it = 0; it < 4; ++it) {
      int idx = it * 64 + lane;
      int row = idx >> 3, ch = idx & 7;
      int tok = iw + row;
      *(uint4*)&aoT[(obase + tok) * HID + h * DHEAD + ch * 8] =
          *(const uint4*)&stw[row * 72 + ch * 8];
    }
  }
}

// ---------------------------------------------------------------------------
extern "C" void kernel_launch(void* const* d_in, const int* in_sizes, int n_in,
                              void* d_out, int out_size, void* d_ws, size_t ws_size,
                              hipStream_t stream) {
  const float* x     = (const float*)d_in[0];
  const float* gamma = (const float*)d_in[1];
  const float* beta  = (const float*)d_in[2];
  const float* wq    = (const float*)d_in[3];
  const float* bq    = (const float*)d_in[4];
  const float* wk    = (const float*)d_in[5];
  const float* bk    = (const float*)d_in[6];
  const float* wv    = (const float*)d_in[7];
  const float* bv    = (const float*)d_in[8];
  const float* wo    = (const float*)d_in[9];
  const float* bo    = (const float*)d_in[10];
  float* out = (float*)d_out;

  const size_t SZ = (size_t)BB * CC * NN_TOK;
  const size_t WZ = (size_t)CC * HID;
  unsigned short* xnT = (unsigned short*)d_ws;      // bf16 [b][tok][c]
  unsigned short* qT  = xnT + SZ;                   // bf16 [b,h,tok,d]
  unsigned short* kT  = qT + SZ;
  unsigned short* vB  = kT + SZ;                    // bf16 [b][c][tok]
  unsigned short* aoT = vB + SZ;                    // bf16 [b][tok][hid]
  unsigned short* wqb = aoT + SZ;
  unsigned short* wkb = wqb + WZ;
  unsigned short* wvb = wkb + WZ;
  unsigned short* wob = wvb + WZ;
  float2* gnpart = (float2*)(wob + WZ);

  wconv_kernel<<<dim3(128, 4), dim3(256), 0, stream>>>(
      wq, wk, wv, wo, wqb, wkb, wvb, wob);

  gn_stats_kernel<<<dim3(256), dim3(256), 0, stream>>>(x, gnpart);
  gn_norm_t_kernel<<<dim3(NN_TOK / 64, CC / 64, BB), dim3(256), 0, stream>>>(
      x, gamma, beta, gnpart, xnT);

  qkv_gemm_kernel<<<dim3(NN_TOK / 128, 12, BB), dim3(256), 0, stream>>>(
      xnT, wqb, wkb, wvb, bq, bk, bv, qT, kT, vB);

  attn_mfma_kernel<<<dim3(NN_TOK / 128, BB * HEADS), dim3(512), 0, stream>>>(
      qT, kT, vB, aoT);

  outproj_kernel<<<dim3(NN_TOK / 64, CC / 128, BB), dim3(256), 0, stream>>>(
      aoT, wob, bo, x, out);
}